// Round 4
// baseline (166992.285 us; speedup 1.0000x reference)
//
#include <hip/hip_runtime.h>
#include <hip/hip_cooperative_groups.h>

namespace cg = cooperative_groups;

typedef __attribute__((ext_vector_type(8))) short bf16x8;
typedef __attribute__((ext_vector_type(4))) float f32x4;

__device__ __forceinline__ float bf2f(unsigned short u){
  union { unsigned int i; float f; } v; v.i = ((unsigned int)u) << 16; return v.f;
}
__device__ __forceinline__ unsigned short f2bf(float f){
  unsigned int u = __float_as_uint(f);
  unsigned int r = (u + 0x7FFFu + ((u >> 16) & 1u)) >> 16;
  return (unsigned short)r;
}
__device__ __forceinline__ float sigm(float x){ return 1.f / (1.f + __expf(-x)); }
__device__ __forceinline__ float ftanh(float x){ float e = __expf(2.f * x); return 1.f - 2.f / (e + 1.f); }

// ---------------- workspace layout (float offsets); total 14,407,936 fl = 57.63 MB ----------------
#define OFF_ENCC    0           // 32*512*128
#define OFF_AH      2097152     // 2*32*1024
#define OFF_AC      2162688     // 32*1024
#define OFF_DH      2195456     // 2*32*1024
#define OFF_DC      2260992     // 32*1024
#define OFF_AW      2293760     // 32*512
#define OFF_CUM     2310144     // 32*512
#define OFF_CTX     2326528     // 32*512
#define OFF_LF      2342912     // 32*512*32
#define OFF_Q       2867200     // 32*128
#define OFF_E       2871296     // 32*512
#define OFF_BAR     2887680     // 256 fl (reserved)
#define OFF_XBUF    2887936     // ushort region: x1hi/x1lo (57344 each), x2hi/x2lo (81920 each) -> 139264 fl
#define OFF_KLOCF   3027200     // 2048
#define OFF_BIAS1   3029248     // 4096
#define OFF_BIAS2   3033344     // 4096
#define OFF_XS16    3037440     // ushort region: 600*32*256 = 4,915,200 ush -> 2,457,600 fl
#define OFF_WP      5495040     // ushort region: wp1 7,340,032 + wp2 10,485,760 ush -> 8,912,896 fl
#define TOTAL_FL    14407936
#define ZERO_BEG    2097152
#define ZERO_CNT    930048      // floats: AH .. XBUF end

struct P {
  const float *enc, *mels, *w_pre1, *w_pre2;
  const float *w_ih1, *w_hh1, *b_ih1, *b_hh1;
  const float *w_q, *b_q, *w_enc, *k_loc, *w_loc, *w_e;
  const float *w_ih2, *w_hh2, *b_ih2, *b_hh2;
  const float *w_mel, *b_mel, *w_stop, *b_stop;
  float *encc;
  float *ah, *ac, *dh, *dc, *aw, *cum, *ctx, *lf, *q, *e;
  float *klocf, *bias1, *bias2;
  unsigned short *xs16, *x1hi, *x1lo, *x2hi, *x2lo, *wp1, *wp2;
  float *out_mel, *out_stop, *out_attn;
};

__global__ void __launch_bounds__(256) k_sentinel(float* out, int n, float v){
  int i = blockIdx.x * 256 + threadIdx.x;
  if (i < n) out[i] = v;
}

// ---------------- setup: fused prenet (whole sequence, teacher-forced) ----------------
__global__ void __launch_bounds__(256) k_prenet(P p){
  __shared__ float in0[2000];   // 25 x 80
  __shared__ float h1[6400];    // 25 x 256
  const int b = blockIdx.x / 24, c = blockIdx.x % 24;
  const int j = threadIdx.x;
  for (int i = j; i < 2000; i += 256){
    const int tt = i / 80, k = i % 80;
    const int t = c * 25 + tt;
    in0[i] = (t == 0) ? 0.f : p.mels[(b * 600 + t - 1) * 80 + k];
  }
  __syncthreads();
  for (int tt = 0; tt < 25; ++tt){
    float acc = 0.f;
    const float* wr = p.w_pre1 + j * 80;
    const float* xr = in0 + tt * 80;
    for (int k = 0; k < 80; ++k) acc += xr[k] * wr[k];
    h1[tt * 256 + j] = fmaxf(acc, 0.f);
  }
  __syncthreads();
  for (int tt = 0; tt < 25; ++tt){
    float acc = 0.f;
    const float* wr = p.w_pre2 + j * 256;
    const float* xr = h1 + tt * 256;
    for (int k = 0; k < 256; k += 4){
      float4 x4 = *(const float4*)(xr + k); float4 w4 = *(const float4*)(wr + k);
      acc += x4.x * w4.x + x4.y * w4.y + x4.z * w4.z + x4.w * w4.w;
    }
    p.xs16[((c * 25 + tt) * 32 + b) * 256 + j] = f2bf(fmaxf(acc, 0.f));
  }
}

// ---------------- setup: enc_cache = enc @ w_enc^T  (fp32) ----------------
__global__ void __launch_bounds__(256) k_encc(P p){
  __shared__ float ex[8192];   // 16 x 512
  const int b = blockIdx.x >> 5, sc = blockIdx.x & 31;
  const int tid = threadIdx.x;
  for (int i = tid; i < 8192; i += 256){
    const int ss = i >> 9, k = i & 511;
    ex[i] = p.enc[((b * 512) + sc * 16 + ss) * 512 + k];
  }
  __syncthreads();
  const int a = tid & 127, sh = tid >> 7;
  const float* wr = p.w_enc + a * 512;
  for (int s8 = 0; s8 < 8; ++s8){
    const int ss = sh * 8 + s8;
    const float* xr = ex + ss * 512;
    float acc = 0.f;
    for (int k = 0; k < 512; k += 4){
      float4 x4 = *(const float4*)(xr + k); float4 w4 = *(const float4*)(wr + k);
      acc += x4.x * w4.x + x4.y * w4.y + x4.z * w4.z + x4.w * w4.w;
    }
    p.encc[((b * 512) + sc * 16 + ss) * 128 + a] = acc;
  }
}

// ---------------- setup: conv kernel re-layout + fused biases ----------------
__global__ void __launch_bounds__(256) k_small(P p){
  const int i = blockIdx.x * 256 + threadIdx.x;
  if (i < 4096){
    p.bias1[i] = p.b_ih1[i] + p.b_hh1[i];
    p.bias2[i] = p.b_ih2[i] + p.b_hh2[i];
  }
  if (i < 2048){
    const int f = i >> 6, cdk = i & 63, cc = cdk >> 5, dk = cdk & 31;
    p.klocf[i] = (dk < 31) ? p.k_loc[(f * 2 + cc) * 31 + dk] : 0.f;
  }
}

// ---------------- setup: pack LSTM weights (fp32 -> bf16) into MFMA B-fragment order ----------------
// row reorder n' = u*4 + gate; element ((nt*KC + kc)*64 + lane)*8 + j = W[n'=nt*16+(lane&15)][k=kc*32+(lane>>4)*8+j]
__global__ void __launch_bounds__(256) k_packw(P p){
  const int stride = gridDim.x * 256;
  for (int i = blockIdx.x * 256 + threadIdx.x; i < 7340032; i += stride){
    const int j = i & 7, rest = i >> 3;
    const int lane = rest & 63, t2 = rest >> 6;
    const int kc = t2 % 56, nt = t2 / 56;
    const int np = nt * 16 + (lane & 15);
    const int k = kc * 32 + (lane >> 4) * 8 + j;
    const int row = (np & 3) * 1024 + (np >> 2);
    p.wp1[i] = f2bf((k < 768) ? p.w_ih1[row * 768 + k] : p.w_hh1[row * 1024 + (k - 768)]);
  }
  for (int i = blockIdx.x * 256 + threadIdx.x; i < 10485760; i += stride){
    const int j = i & 7, rest = i >> 3;
    const int lane = rest & 63, t2 = rest >> 6;
    const int kc = t2 % 80, nt = t2 / 80;
    const int np = nt * 16 + (lane & 15);
    const int k = kc * 32 + (lane >> 4) * 8 + j;
    const int row = (np & 3) * 1024 + (np >> 2);
    p.wp2[i] = f2bf((k < 1536) ? p.w_ih2[row * 1536 + k] : p.w_hh2[row * 1024 + (k - 1536)]);
  }
}

// ---------------- setup: xs part of X1(0) ----------------
__global__ void __launch_bounds__(256) k_packx0(P p){
  const int i = blockIdx.x * 256 + threadIdx.x;
  if (i >= 8192) return;
  const int b = i >> 8, k = i & 255;
  p.x1hi[b * 1792 + k] = p.xs16[b * 256 + k];   // lo slots stay 0 (memset)
}

// ---------------- the persistent decoder: 256 blocks x 512 threads, cooperative ----------------
__global__ void __launch_bounds__(512, 2) k_decoder(P p){
  cg::grid_group grid = cg::this_grid();
  const int blk = blockIdx.x;
  const int tid = threadIdx.x;
  const int gtid = blk * 512 + tid;
  __shared__ float sm[8192];

  for (int t = 0; t <= 600; ++t){
    const int pn = (t + 1) & 1;

    // ===== Phase M: LSTM1(t) [waves 0-3] and LSTM2(t-1) [waves 4-7], MFMA =====
    {
      const bool is2 = (tid >= 256);
      const int tt = tid & 255;
      const int w = tt >> 6, lane = tt & 63;
      const int mt = w >> 1, kh = w & 1;
      const int col = lane & 15, q4 = lane >> 4;
      const int nt = (blk >> 3) + (blk & 7) * 32;      // XCD-partitioned N-tile
      const bool active = is2 ? (t > 0) : (t < 600);
      f32x4 acc; acc.x = 0.f; acc.y = 0.f; acc.z = 0.f; acc.w = 0.f;
      if (active){
        const int m = mt * 16 + col;
        const unsigned short *xh, *xl, *wp;
        int kcBeg, kcEnd, astr;
        if (!is2){ xh = p.x1hi; xl = p.x1lo; wp = p.wp1 + nt * 56 * 512; astr = 1792; kcBeg = kh * 28; kcEnd = kcBeg + 28; }
        else     { xh = p.x2hi; xl = p.x2lo; wp = p.wp2 + nt * 80 * 512; astr = 2560; kcBeg = kh * 40; kcEnd = kcBeg + 40; }
        xh += m * astr + q4 * 8;  xl += m * astr + q4 * 8;  wp += lane * 8;
        for (int kc = kcBeg; kc < kcEnd; ++kc){
          bf16x8 a0 = *(const bf16x8*)(xh + kc * 32);
          bf16x8 a1 = *(const bf16x8*)(xl + kc * 32);
          bf16x8 bw = *(const bf16x8*)(wp + kc * 512);
          acc = __builtin_amdgcn_mfma_f32_16x16x32_bf16(a0, bw, acc, 0, 0, 0);
          acc = __builtin_amdgcn_mfma_f32_16x16x32_bf16(a1, bw, acc, 0, 0, 0);
        }
      }
      float* red = sm + (is2 ? 512 : 0);
      if (active && kh == 1){
        red[mt * 256 + lane * 4 + 0] = acc.x;
        red[mt * 256 + lane * 4 + 1] = acc.y;
        red[mt * 256 + lane * 4 + 2] = acc.z;
        red[mt * 256 + lane * 4 + 3] = acc.w;
      }
      __syncthreads();
      if (active && kh == 0){
        acc.x += red[mt * 256 + lane * 4 + 0];
        acc.y += red[mt * 256 + lane * 4 + 1];
        acc.z += red[mt * 256 + lane * 4 + 2];
        acc.w += red[mt * 256 + lane * 4 + 3];
        float vi[4], vf[4], vg[4], vo[4];
        #pragma unroll
        for (int r = 0; r < 4; ++r){
          float a = (r == 0) ? acc.x : (r == 1) ? acc.y : (r == 2) ? acc.z : acc.w;
          float b1 = __shfl_xor(a, 1);
          float b2 = __shfl_xor(a, 2);
          float b3 = __shfl_xor(b1, 2);
          vi[r] = a; vf[r] = b1; vg[r] = b2; vo[r] = b3;
        }
        if ((col & 3) == 0){
          const int u = nt * 4 + (col >> 2);
          const float* bias = is2 ? p.bias2 : p.bias1;
          const float bi = bias[u], bfv = bias[1024 + u], bg = bias[2048 + u], bo = bias[3072 + u];
          float* cbuf = is2 ? p.dc : p.ac;
          float* hbuf = (is2 ? p.dh : p.ah) + pn * 32768;
          #pragma unroll
          for (int r = 0; r < 4; ++r){
            const int br = mt * 16 + q4 * 4 + r;
            float c_ = sigm(vf[r] + bfv) * cbuf[br * 1024 + u] + sigm(vi[r] + bi) * ftanh(vg[r] + bg);
            cbuf[br * 1024 + u] = c_;
            hbuf[br * 1024 + u] = sigm(vo[r] + bo) * ftanh(c_);
          }
        }
      }
    }
    grid.sync();

    // ===== Phase B: q(t), output proj(t-1), repack ah/dh parts of X1/X2 =====
    if (t < 600 && gtid < 8192){
      const int b = gtid >> 8, r = gtid & 255, a = r >> 1, hf = r & 1;
      const float* xv = p.ah + pn * 32768 + b * 1024 + hf * 512;
      const float* wv = p.w_q + a * 1024 + hf * 512;
      float s = 0.f;
      for (int k = 0; k < 512; k += 4){
        float4 x4 = *(const float4*)(xv + k); float4 w4 = *(const float4*)(wv + k);
        s += x4.x * w4.x + x4.y * w4.y + x4.z * w4.z + x4.w * w4.w;
      }
      s += __shfl_xor(s, 1);
      if (hf == 0) p.q[b * 128 + a] = s + p.b_q[a];
    }
    if (t > 0 && gtid >= 8192 && gtid < 13376){
      const int pidx0 = gtid - 8192;
      const int pidx = pidx0 >> 1, hf = pidx0 & 1;
      const float* dhv = p.dh + pn * 32768;
      const float* wr; int b2; bool isMel; int m2 = 0;
      if (pidx < 2560){ b2 = pidx / 80; m2 = pidx % 80; wr = p.w_mel + m2 * 1536 + hf * 768; isMel = true; }
      else            { b2 = pidx - 2560; wr = p.w_stop + hf * 768; isMel = false; }
      const float* xr0 = dhv + b2 * 1024;
      float s = 0.f;
      if (hf == 0){
        for (int k = 0; k < 768; k += 4){
          float4 x4 = *(const float4*)(xr0 + k); float4 w4 = *(const float4*)(wr + k);
          s += x4.x * w4.x + x4.y * w4.y + x4.z * w4.z + x4.w * w4.w;
        }
      } else {
        const float* xr1 = xr0 + 768;
        for (int k = 0; k < 256; k += 4){
          float4 x4 = *(const float4*)(xr1 + k); float4 w4 = *(const float4*)(wr + k);
          s += x4.x * w4.x + x4.y * w4.y + x4.z * w4.z + x4.w * w4.w;
        }
        const float* xr2 = p.ctx + b2 * 512;
        for (int k = 0; k < 512; k += 4){
          float4 x4 = *(const float4*)(xr2 + k); float4 w4 = *(const float4*)(wr + 256 + k);
          s += x4.x * w4.x + x4.y * w4.y + x4.z * w4.z + x4.w * w4.w;
        }
      }
      s += __shfl_xor(s, 1);
      if (hf == 0){
        if (isMel) p.out_mel[(b2 * 600 + (t - 1)) * 80 + m2] = s + p.b_mel[m2];
        else       p.out_stop[b2 * 600 + (t - 1)] = s + p.b_stop[0];
      }
    }
    if (t < 600 && gtid >= 16384 && gtid < 114688){
      const int id = gtid - 16384;           // 98304 jobs
      const int b = id / 3072, kk = id % 3072;
      const float* ahv = p.ah + pn * 32768;
      const float* dhv = p.dh + pn * 32768;
      float v; unsigned short *hb, *lb; int slot;
      if (kk < 1024){ v = ahv[b * 1024 + kk]; hb = p.x1hi; lb = p.x1lo; slot = b * 1792 + 768 + kk; }
      else if (kk < 2048){ const int k2 = kk - 1024; v = ahv[b * 1024 + k2]; hb = p.x2hi; lb = p.x2lo; slot = b * 2560 + k2; }
      else { const int k2 = kk - 2048; v = dhv[b * 1024 + k2]; hb = p.x2hi; lb = p.x2lo; slot = b * 2560 + 1536 + k2; }
      const unsigned short h = f2bf(v);
      hb[slot] = h; lb[slot] = f2bf(v - bf2f(h));
    }
    if (t == 600) break;
    grid.sync();

    // ===== Phase C: e[b][s] = w_e . tanh(q + encc + lf @ w_loc^T) =====
    {
      const int b = blk >> 3, sc = blk & 7;
      const int a = tid & 127, sl = tid >> 7;
      float wl[32];
      {
        const float* wr = p.w_loc + a * 32;
        #pragma unroll
        for (int i = 0; i < 32; i += 4){
          float4 v4 = *(const float4*)(wr + i);
          wl[i] = v4.x; wl[i+1] = v4.y; wl[i+2] = v4.z; wl[i+3] = v4.w;
        }
      }
      const float qa = p.q[b * 128 + a];
      const float wea = p.w_e[a];
      float* red = sm;   // [64][128]
      for (int si = 0; si < 16; ++si){
        const int srow = sl * 16 + si;
        const int s = sc * 64 + srow;
        float v = qa + p.encc[(b * 512 + s) * 128 + a];
        const float* lfr = p.lf + (b * 512 + s) * 32;
        #pragma unroll
        for (int i = 0; i < 32; i += 4){
          float4 l4 = *(const float4*)(lfr + i);
          v += l4.x * wl[i] + l4.y * wl[i+1] + l4.z * wl[i+2] + l4.w * wl[i+3];
        }
        red[srow * 128 + a] = ftanh(v) * wea;
      }
      __syncthreads();
      const int i2 = tid >> 3, p8 = tid & 7;
      float ssum = 0.f;
      const float* rr = red + i2 * 128 + p8 * 16;
      #pragma unroll
      for (int k = 0; k < 16; ++k) ssum += rr[k];
      ssum += __shfl_xor(ssum, 1); ssum += __shfl_xor(ssum, 2); ssum += __shfl_xor(ssum, 4);
      if (p8 == 0) p.e[b * 512 + sc * 64 + i2] = ssum;
    }
    grid.sync();

    // ===== Phase D: softmax -> aw, cum, attn out; xs-part repack of X1(t+1) =====
    if (gtid < 2048){
      const int b = gtid >> 6, ln = gtid & 63;
      const float* er = p.e + b * 512 + ln * 8;
      float v[8];
      #pragma unroll
      for (int i = 0; i < 8; ++i) v[i] = er[i];
      float mx = v[0];
      #pragma unroll
      for (int i = 1; i < 8; ++i) mx = fmaxf(mx, v[i]);
      for (int off = 1; off < 64; off <<= 1) mx = fmaxf(mx, __shfl_xor(mx, off));
      float w8[8]; float ps = 0.f;
      #pragma unroll
      for (int i = 0; i < 8; ++i){ w8[i] = __expf(v[i] - mx); ps += w8[i]; }
      for (int off = 1; off < 64; off <<= 1) ps += __shfl_xor(ps, off);
      const float inv = 1.f / ps;
      float* ao = p.out_attn + (b * 600 + t) * 512 + ln * 8;
      float* awp = p.aw + b * 512 + ln * 8;
      float* cup = p.cum + b * 512 + ln * 8;
      #pragma unroll
      for (int i = 0; i < 8; ++i){
        const float awv = w8[i] * inv;
        awp[i] = awv; cup[i] += awv; ao[i] = awv;
      }
    } else if (gtid >= 2048 && gtid < 10240){
      const int id = gtid - 2048;
      const int b = id >> 8, k = id & 255;
      const unsigned short h = (t + 1 < 600) ? p.xs16[((t + 1) * 32 + b) * 256 + k] : (unsigned short)0;
      p.x1hi[b * 1792 + k] = h;   // lo slots for xs region remain 0
    }
    grid.sync();

    // ===== Phase E: ctx (XCD-aligned d-chunks) + ctx repack; conv -> lf(t+1) =====
    {
      const int b = blk >> 3, x = blk & 7;
      const int s4 = tid >> 6, dl = tid & 63;
      const int d = x * 64 + dl;
      const float* awr = p.aw + b * 512 + s4 * 64;
      const float* er = p.enc + (b * 512 + s4 * 64) * 512 + d;
      float s = 0.f;
      for (int ss = 0; ss < 64; ++ss) s += awr[ss] * er[ss * 512];
      sm[s4 * 64 + dl] = s;
      __syncthreads();
      if (tid < 64){
        const int d2 = x * 64 + tid;
        float r0 = 0.f;
        #pragma unroll
        for (int j2 = 0; j2 < 8; ++j2) r0 += sm[j2 * 64 + tid];
        p.ctx[b * 512 + d2] = r0;
        const unsigned short h = f2bf(r0);
        const unsigned short l = f2bf(r0 - bf2f(h));
        p.x1hi[b * 1792 + 256 + d2] = h;  p.x1lo[b * 1792 + 256 + d2] = l;
        p.x2hi[b * 2560 + 1024 + d2] = h; p.x2lo[b * 2560 + 1024 + d2] = l;
      }
      if (tid >= 256 && tid < 384){
        const int id = blk * 128 + (tid - 256);  // 0..32767
        const int b2 = id >> 10, r = id & 1023, s2 = r >> 1, fh = r & 1;
        float va[31], vc[31];
        #pragma unroll
        for (int dk = 0; dk < 31; ++dk){
          const int idx = s2 + dk - 15;
          const bool ok = (idx >= 0) && (idx < 512);
          va[dk] = ok ? p.aw[b2 * 512 + idx] : 0.f;
          vc[dk] = ok ? p.cum[b2 * 512 + idx] : 0.f;
        }
        for (int f0 = 0; f0 < 16; ++f0){
          const int f = fh * 16 + f0;
          const float* kA = p.klocf + f * 64;
          const float* kB = kA + 32;
          float acc2 = 0.f;
          #pragma unroll
          for (int dk = 0; dk < 31; ++dk) acc2 += kA[dk] * va[dk] + kB[dk] * vc[dk];
          p.lf[(b2 * 512 + s2) * 32 + f] = acc2;
        }
      }
    }
    grid.sync();
  }
}

extern "C" void kernel_launch(void* const* d_in, const int* in_sizes, int n_in,
                              void* d_out, int out_size, void* d_ws, size_t ws_size,
                              hipStream_t stream){
  float* outp = (float*)d_out;

  // Diagnostic sentinel: workspace too small -> error ~= 1.0 on output 0
  if (ws_size < (size_t)TOTAL_FL * 4){
    hipLaunchKernelGGL(k_sentinel, dim3(16), dim3(256), 0, stream, outp, 4096, 1.0f);
    return;
  }

  P p;
  p.enc    = (const float*)d_in[0];
  p.mels   = (const float*)d_in[2];
  p.w_pre1 = (const float*)d_in[3];
  p.w_pre2 = (const float*)d_in[4];
  p.w_ih1  = (const float*)d_in[5];
  p.w_hh1  = (const float*)d_in[6];
  p.b_ih1  = (const float*)d_in[7];
  p.b_hh1  = (const float*)d_in[8];
  p.w_q    = (const float*)d_in[9];
  p.b_q    = (const float*)d_in[10];
  p.w_enc  = (const float*)d_in[11];
  p.k_loc  = (const float*)d_in[12];
  p.w_loc  = (const float*)d_in[13];
  p.w_e    = (const float*)d_in[14];
  p.w_ih2  = (const float*)d_in[15];
  p.w_hh2  = (const float*)d_in[16];
  p.b_ih2  = (const float*)d_in[17];
  p.b_hh2  = (const float*)d_in[18];
  p.w_mel  = (const float*)d_in[19];
  p.b_mel  = (const float*)d_in[20];
  p.w_stop = (const float*)d_in[21];
  p.b_stop = (const float*)d_in[22];

  float* ws = (float*)d_ws;
  p.encc = ws + OFF_ENCC;
  p.ah   = ws + OFF_AH;    p.ac   = ws + OFF_AC;
  p.dh   = ws + OFF_DH;    p.dc   = ws + OFF_DC;
  p.aw   = ws + OFF_AW;    p.cum  = ws + OFF_CUM;  p.ctx = ws + OFF_CTX;
  p.lf   = ws + OFF_LF;    p.q    = ws + OFF_Q;    p.e   = ws + OFF_E;
  p.klocf = ws + OFF_KLOCF;
  p.bias1 = ws + OFF_BIAS1; p.bias2 = ws + OFF_BIAS2;
  unsigned short* xb = (unsigned short*)(ws + OFF_XBUF);
  p.x1hi = xb;             p.x1lo = xb + 57344;
  p.x2hi = xb + 114688;    p.x2lo = xb + 196608;
  p.xs16 = (unsigned short*)(ws + OFF_XS16);
  unsigned short* wpb = (unsigned short*)(ws + OFF_WP);
  p.wp1  = wpb;            p.wp2  = wpb + 7340032;

  p.out_mel  = outp;
  p.out_stop = outp + 1536000;
  p.out_attn = outp + 1555200;

  hipMemsetAsync((void*)(ws + ZERO_BEG), 0, (size_t)ZERO_CNT * 4, stream);
  hipLaunchKernelGGL(k_prenet, dim3(768), dim3(256), 0, stream, p);
  hipLaunchKernelGGL(k_encc,   dim3(1024), dim3(256), 0, stream, p);
  hipLaunchKernelGGL(k_small,  dim3(16), dim3(256), 0, stream, p);
  hipLaunchKernelGGL(k_packw,  dim3(2048), dim3(256), 0, stream, p);
  hipLaunchKernelGGL(k_packx0, dim3(32), dim3(256), 0, stream, p);

  void* args[] = { &p };
  hipError_t err = hipLaunchCooperativeKernel((void*)k_decoder, dim3(256), dim3(512), args, 0, stream);
  if (err != hipSuccess){
    // Diagnostic sentinel: cooperative launch rejected -> error ~= 4.0 on output 0
    hipLaunchKernelGGL(k_sentinel, dim3(16), dim3(256), 0, stream, outp, 4096, 4.0f);
  }
}